// Round 1
// baseline (392.754 us; speedup 1.0000x reference)
//
#include <hip/hip_runtime.h>

#define BATCH 16
#define CIN   12
#define HH    256
#define WW    256
#define KK    9
#define HO    254
#define WO    254
#define PIX   (HO*WO)          // 64516
#define COUT  16

// LDS weight layouts: [k][c][o] with o contiguous so unrolled o-loops become
// float4 (ds_read_b128) broadcasts.
//   wc: o in [0,18) -> w0 (offset conv), [18,27) -> w2 (mask conv), 27 pad
//   e1: w1 (deform conv 1), e2: w3 (deform conv 2)
__global__ __launch_bounds__(256) void dcn_fused(
    const float* __restrict__ x,
    const float* __restrict__ w0, const float* __restrict__ b0,
    const float* __restrict__ w1, const float* __restrict__ b1,
    const float* __restrict__ w2, const float* __restrict__ b2,
    const float* __restrict__ w3, const float* __restrict__ b3,
    float* __restrict__ out)
{
    __shared__ float wc[KK*CIN*28];
    __shared__ float e1[KK*CIN*16];
    __shared__ float e2[KK*CIN*16];

    const int tid = threadIdx.y*16 + threadIdx.x;

    for (int i = tid; i < KK*CIN*28; i += 256) {
        int k = i / (CIN*28);
        int r = i % (CIN*28);
        int c = r / 28;
        int o = r % 28;
        float v = 0.f;
        if (o < 18)      v = w0[(o*CIN + c)*KK + k];
        else if (o < 27) v = w2[((o-18)*CIN + c)*KK + k];
        wc[i] = v;
    }
    for (int i = tid; i < KK*CIN*16; i += 256) {
        int k = i / (CIN*16);
        int r = i % (CIN*16);
        int c = r / 16;
        int o = r % 16;
        e1[i] = w1[(o*CIN + c)*KK + k];
        e2[i] = w3[(o*CIN + c)*KK + k];
    }
    __syncthreads();

    const int b  = blockIdx.z;
    const int ho = blockIdx.y*16 + threadIdx.y;
    const int wo = blockIdx.x*16 + threadIdx.x;
    if (ho >= HO || wo >= WO) return;

    const float* xb = x + (size_t)b*CIN*HH*WW;

    // ---- phase 1: offset (18) + mask-logit (9) convs ----
    float off[28];
    #pragma unroll
    for (int o = 0; o < 18; ++o) off[o] = b0[o];
    #pragma unroll
    for (int o = 0; o < 9;  ++o) off[18+o] = b2[o];
    off[27] = 0.f;

    {
        const float* xp = xb + ho*WW + wo;
        for (int c = 0; c < CIN; ++c) {
            const float* xc = xp + c*HH*WW;
            #pragma unroll
            for (int ky = 0; ky < 3; ++ky) {
                #pragma unroll
                for (int kx = 0; kx < 3; ++kx) {
                    const float v = xc[ky*WW + kx];
                    const int k = ky*3 + kx;
                    const float4* wrow = (const float4*)&wc[(k*CIN + c)*28];
                    #pragma unroll
                    for (int q = 0; q < 7; ++q) {
                        float4 w4 = wrow[q];
                        off[4*q+0] += w4.x * v;
                        off[4*q+1] += w4.y * v;
                        off[4*q+2] += w4.z * v;
                        off[4*q+3] += w4.w * v;
                    }
                }
            }
        }
    }

    float m[9];
    #pragma unroll
    for (int j = 0; j < 9; ++j) m[j] = 1.f / (1.f + expf(-off[18+j]));

    // ---- phase 2: deformable sampling + dual einsum ----
    float acc1[16], acc2[16];
    #pragma unroll
    for (int o = 0; o < 16; ++o) { acc1[o] = b1[o]; acc2[o] = b3[o]; }

    #pragma unroll
    for (int k = 0; k < 9; ++k) {
        const float py = off[2*k]   + (float)(k/3) + (float)ho;
        const float px = off[2*k+1] + (float)(k%3) + (float)wo;
        const float y0f = floorf(py), x0f = floorf(px);
        const float fy = py - y0f, fx = px - x0f;
        const int y0 = (int)y0f, x0i = (int)x0f;
        const int y1 = y0 + 1,  x1i = x0i + 1;

        float w00 = (1.f-fy)*(1.f-fx);
        float w01 = (1.f-fy)*fx;
        float w10 = fy*(1.f-fx);
        float w11 = fy*fx;

        const bool vy0 = (unsigned)y0  < HH;
        const bool vy1 = (unsigned)y1  < HH;
        const bool vx0 = (unsigned)x0i < WW;
        const bool vx1 = (unsigned)x1i < WW;
        if (!(vy0 && vx0)) w00 = 0.f;
        if (!(vy0 && vx1)) w01 = 0.f;
        if (!(vy1 && vx0)) w10 = 0.f;
        if (!(vy1 && vx1)) w11 = 0.f;

        const int cy0 = min(max(y0, 0),  HH-1);
        const int cy1 = min(max(y1, 0),  HH-1);
        const int cx0 = min(max(x0i, 0), WW-1);
        const int cx1 = min(max(x1i, 0), WW-1);
        const int i00 = cy0*WW + cx0;
        const int i01 = cy0*WW + cx1;
        const int i10 = cy1*WW + cx0;
        const int i11 = cy1*WW + cx1;

        const float mk = m[k];

        for (int c = 0; c < CIN; ++c) {
            const float* xc = xb + c*(HH*WW);
            const float v = w00*xc[i00] + w01*xc[i01] + w10*xc[i10] + w11*xc[i11];
            const float vm = v * mk;
            const float4* w1r = (const float4*)&e1[(k*CIN + c)*16];
            const float4* w3r = (const float4*)&e2[(k*CIN + c)*16];
            #pragma unroll
            for (int q = 0; q < 4; ++q) {
                float4 a  = w1r[q];
                float4 bb = w3r[q];
                acc1[4*q+0] += a.x  * v;
                acc1[4*q+1] += a.y  * v;
                acc1[4*q+2] += a.z  * v;
                acc1[4*q+3] += a.w  * v;
                acc2[4*q+0] += bb.x * vm;
                acc2[4*q+1] += bb.y * vm;
                acc2[4*q+2] += bb.z * vm;
                acc2[4*q+3] += bb.w * vm;
            }
        }
    }

    // ---- store: x1 then x2, each [B][16][254][254] ----
    const size_t p = (size_t)ho*WO + wo;
    float* o1 = out + (size_t)b*COUT*PIX + p;
    float* o2 = o1 + (size_t)BATCH*COUT*PIX;
    #pragma unroll
    for (int o = 0; o < 16; ++o) {
        o1[(size_t)o*PIX] = acc1[o];
        o2[(size_t)o*PIX] = acc2[o];
    }
}

extern "C" void kernel_launch(void* const* d_in, const int* in_sizes, int n_in,
                              void* d_out, int out_size, void* d_ws, size_t ws_size,
                              hipStream_t stream) {
    const float* x  = (const float*)d_in[0];
    const float* w0 = (const float*)d_in[1];
    const float* b0 = (const float*)d_in[2];
    const float* w1 = (const float*)d_in[3];
    const float* b1 = (const float*)d_in[4];
    const float* w2 = (const float*)d_in[5];
    const float* b2 = (const float*)d_in[6];
    const float* w3 = (const float*)d_in[7];
    const float* b3 = (const float*)d_in[8];
    float* out = (float*)d_out;

    dim3 block(16, 16);
    dim3 grid((WO + 15)/16, (HO + 15)/16, BATCH);
    dcn_fused<<<grid, block, 0, stream>>>(x, w0, b0, w1, b1, w2, b2, w3, b3, out);
}